// Round 9
// baseline (524.003 us; speedup 1.0000x reference)
//
#include <hip/hip_runtime.h>
#include <math.h>

#define NBINS 255
#define BIN_LO_F (-20.0f)
#define BIN_HI_F (20.0f)

typedef __attribute__((ext_vector_type(8))) short short8;
typedef __attribute__((ext_vector_type(16))) float f32x16;

__device__ __forceinline__ unsigned short f2bf(float f) {
    unsigned u = __builtin_bit_cast(unsigned, f);
    unsigned r = u + 0x7fffu + ((u >> 16) & 1u);
    return (unsigned short)(r >> 16);
}

__device__ __forceinline__ unsigned pkbf(float lo, float hi) {
    unsigned d;
    asm("v_cvt_pk_bf16_f32 %0, %1, %2" : "=v"(d) : "v"(lo), "v"(hi));
    return d;
}

__device__ __forceinline__ short8 mk8(unsigned a, unsigned b, unsigned c, unsigned d) {
    union { unsigned u[4]; short8 s; } t;
    t.u[0] = a; t.u[1] = b; t.u[2] = c; t.u[3] = d;
    return t.s;
}

__device__ __forceinline__ void glds16(const void* g, void* l) {
    __builtin_amdgcn_global_load_lds(
        (const __attribute__((address_space(1))) unsigned int*)g,
        (__attribute__((address_space(3))) unsigned int*)l, 16, 0, 0);
}

__device__ __forceinline__ double wave_reduce_sum_d(double v) {
    #pragma unroll
    for (int m = 32; m >= 1; m >>= 1) v += __shfl_xor(v, m, 64);
    return v;
}

#define WAITN(n) asm volatile("s_waitcnt vmcnt(" #n ")" ::: "memory")
template<int N> __device__ __forceinline__ void WVN() {
    if constexpr (N == 15) WAITN(15);
    else if constexpr (N == 12) WAITN(12);
    else if constexpr (N == 10) WAITN(10);
    else if constexpr (N == 8)  WAITN(8);
    else if constexpr (N == 5)  WAITN(5);
    else if constexpr (N == 4)  WAITN(4);
    else if constexpr (N == 3)  WAITN(3);
    else if constexpr (N == 2)  WAITN(2);
    else if constexpr (N == 1)  WAITN(1);
    else if constexpr (N == 0)  WAITN(0);
}

// Pack W (D,255) fp32 -> bf16 image, one 16 KB block per K-step of 32 (see r8).
__global__ __launch_bounds__(256) void pack_w4(
    const float* __restrict__ W, char* __restrict__ WpackB)
{
    int u = blockIdx.x * 256 + threadIdx.x;
    int kt = u >> 10;
    int v  = u & 1023;
    int ks = v >> 9;
    int lh = (v >> 8) & 1;
    int gcol = (v >> 5) & 7;
    int c31  = v & 31;
    int col  = gcol * 32 + c31;
    int k0   = kt * 32 + ks * 16 + lh * 8;
    short8 s;
    #pragma unroll
    for (int e = 0; e < 8; ++e)
        s[e] = (col < NBINS) ? (short)f2bf(W[(size_t)(k0 + e) * NBINS + col]) : (short)0;
    *(short8*)(WpackB + (size_t)u * 16) = s;
}

// Ablation-instrumented v8 GEMM. V=0 full/real; V=1 stage A+B only; V=2 stage-B only;
// V=3 stage-A only; V=4 compute-only (garbage LDS). Sync structure identical across V.
template<int V>
__global__ __launch_bounds__(256, 2) void gemm_abl(
    const float* __restrict__ latents, const float* __restrict__ boot,
    const char* __restrict__ WpackB, const float* __restrict__ bvec,
    float* __restrict__ logits, int NR, int R, int D, int nwg8)
{
    constexpr bool DO_A = (V == 0) || (V == 1) || (V == 3);
    constexpr bool DO_B = (V == 0) || (V == 1) || (V == 2);
    constexpr bool DO_C = (V == 0) || (V == 4);
    constexpr int  BATCH = (DO_A ? 1 : 0) + (DO_B ? 4 : 0);

    __shared__ __align__(16) char ldsA[4][4096];
    __shared__ __align__(16) char ldsB[4][16384];

    const int tid  = threadIdx.x;
    const int wave = tid >> 6, lane = tid & 63;
    const int l31  = lane & 31, lhi = lane >> 5;
    const int NT   = D >> 5;

    int bid  = blockIdx.x;
    int work = (bid & 7) * nwg8 + (bid >> 3);
    const int row0 = work * 32;

    const int arow_loc = (wave << 3) + (lane >> 3);
    const int arow = row0 + arow_loc;
    const float* arowp = (arow < NR) ? latents + (size_t)arow * D
                                     : boot + (size_t)(arow - NR) * D;
    const float* asrc = arowp + (((lane & 7) ^ (arow_loc & 7)) << 2);

    const int abase = l31 << 7;
    const int axor  = l31 & 7;

    f32x16 acc0, acc1;
    #pragma unroll
    for (int r = 0; r < 16; ++r) { acc0[r] = 0.f; acc1[r] = 0.f; }

#define STAGE(T, BUF) do {                                                  \
        if constexpr (DO_A)                                                 \
            glds16(asrc + (size_t)(T) * 32, &ldsA[BUF][(wave << 10) + (lane << 4)]); \
        if constexpr (DO_B) {                                               \
            const char* bs_ = WpackB + (size_t)(T) * 16384 + (wave << 12) + (lane << 4); \
            char* bd_ = &ldsB[BUF][(wave << 12) + (lane << 4)];             \
            glds16(bs_,        bd_);                                        \
            glds16(bs_ + 1024, bd_ + 1024);                                 \
            glds16(bs_ + 2048, bd_ + 2048);                                 \
            glds16(bs_ + 3072, bd_ + 3072);                                 \
        }                                                                   \
    } while (0)

#define COMPUTE(BUF) do {                                                   \
        if constexpr (DO_C) {                                               \
            const char* ab_ = &ldsA[BUF][0];                                \
            const char* bb_ = &ldsB[BUF][0] + (wave << 10) + (l31 << 4);    \
            _Pragma("unroll")                                               \
            for (int ks = 0; ks < 2; ++ks) {                                \
                int c0_ = ks * 4 + lhi * 2;                                 \
                float4 f0_ = *(const float4*)(ab_ + abase + (((c0_ + 0) ^ axor) << 4)); \
                float4 f1_ = *(const float4*)(ab_ + abase + (((c0_ + 1) ^ axor) << 4)); \
                short8 a_  = mk8(pkbf(f0_.x, f0_.y), pkbf(f0_.z, f0_.w),    \
                                 pkbf(f1_.x, f1_.y), pkbf(f1_.z, f1_.w));   \
                short8 b0_ = *(const short8*)(bb_ + ((ks * 2 + lhi) << 12)); \
                short8 b1_ = *(const short8*)(bb_ + ((ks * 2 + lhi) << 12) + 512); \
                acc0 = __builtin_amdgcn_mfma_f32_32x32x16_bf16(a_, b0_, acc0, 0, 0, 0); \
                acc1 = __builtin_amdgcn_mfma_f32_32x32x16_bf16(a_, b1_, acc1, 0, 0, 0); \
            }                                                               \
        }                                                                   \
    } while (0)

#define BAR()   __builtin_amdgcn_s_barrier()
#define SCHED() __builtin_amdgcn_sched_barrier(0)

    if constexpr (BATCH > 0) { STAGE(0, 0); STAGE(1, 1); STAGE(2, 2); }

    int t = 0;
    for (; t + 7 < NT; t += 4) {
        BAR(); SCHED(); STAGE(t + 3, 3); SCHED();
        if constexpr (BATCH > 0) WVN<3 * BATCH>();
        BAR(); SCHED(); COMPUTE(0);
        BAR(); SCHED(); STAGE(t + 4, 0); SCHED();
        if constexpr (BATCH > 0) WVN<3 * BATCH>();
        BAR(); SCHED(); COMPUTE(1);
        BAR(); SCHED(); STAGE(t + 5, 1); SCHED();
        if constexpr (BATCH > 0) WVN<3 * BATCH>();
        BAR(); SCHED(); COMPUTE(2);
        BAR(); SCHED(); STAGE(t + 6, 2); SCHED();
        if constexpr (BATCH > 0) WVN<3 * BATCH>();
        BAR(); SCHED(); COMPUTE(3);
    }
    BAR(); SCHED(); STAGE(t + 3, 3); SCHED();
    if constexpr (BATCH > 0) WVN<3 * BATCH>();
    BAR(); SCHED(); COMPUTE(0);
    BAR(); SCHED(); if constexpr (BATCH > 0) WVN<2 * BATCH>();
    BAR(); SCHED(); COMPUTE(1);
    BAR(); SCHED(); if constexpr (BATCH > 0) WVN<1 * BATCH>();
    BAR(); SCHED(); COMPUTE(2);
    BAR(); SCHED(); if constexpr (BATCH > 0) WVN<0>();
    BAR(); SCHED(); COMPUTE(3);

#undef STAGE
#undef COMPUTE
#undef BAR
#undef SCHED

    if constexpr (DO_C) {
        #pragma unroll
        for (int i = 0; i < 2; ++i) {
            int col = wave * 64 + i * 32 + l31;
            if (col < NBINS) {
                float bias = bvec[col];
                const f32x16& a = i ? acc1 : acc0;
                #pragma unroll
                for (int r = 0; r < 16; ++r) {
                    int row = row0 + (r & 3) + 8 * (r >> 2) + 4 * lhi;
                    logits[(size_t)row * NBINS + col] = a[r] + bias;
                }
            }
        }
    } else {
        // keep the staged LDS observable so nothing is DCE'd; essentially never stores
        volatile float* pa = (volatile float*)&ldsA[0][0];
        volatile float* pb = (volatile float*)&ldsB[0][0];
        float tok = pa[tid & 255] + pb[tid];
        if (tok == 123456.78125f && lane == 0)
            logits[(size_t)work * 4 + wave] = tok;
    }
}

__global__ __launch_bounds__(256) void softmax_stats(
    const float* __restrict__ logits, float* __restrict__ values,
    float* __restrict__ logZ, int R)
{
    int row  = blockIdx.x * 4 + (threadIdx.x >> 6);
    int lane = threadIdx.x & 63;
    if (row >= R) return;
    const float* lp = logits + (size_t)row * NBINS;
    const float step = (float)(40.0 / 254.0);

    float l[4];
    float m = -INFINITY;
    #pragma unroll
    for (int u = 0; u < 4; ++u) {
        int idx = lane + 64 * u;
        l[u] = (idx < NBINS) ? lp[idx] : -INFINITY;
        m = fmaxf(m, l[u]);
    }
    #pragma unroll
    for (int sh = 32; sh >= 1; sh >>= 1) m = fmaxf(m, __shfl_xor(m, sh, 64));

    float s = 0.f, sc = 0.f;
    #pragma unroll
    for (int u = 0; u < 4; ++u) {
        int idx = lane + 64 * u;
        if (idx < NBINS) {
            float e = __expf(l[u] - m);
            s  += e;
            sc += e * (BIN_LO_F + step * (float)idx);
        }
    }
    #pragma unroll
    for (int sh = 32; sh >= 1; sh >>= 1) {
        s  += __shfl_xor(s, sh, 64);
        sc += __shfl_xor(sc, sh, 64);
    }
    if (lane == 0) {
        values[row] = sc / s;
        logZ[row]   = m + __logf(s);
    }
}

__global__ void lambda_returns_k(
    const float* __restrict__ rewards, const float* __restrict__ dones,
    const float* __restrict__ values, float* __restrict__ returns,
    int B, int H, int NR)
{
    int b = blockIdx.x * blockDim.x + threadIdx.x;
    if (b >= B) return;
    const float gamma = 0.997f;
    const float lam   = 0.95f;
    const float oml   = (float)(1.0 - 0.95);
    float bootv = values[NR + b];
    float g = bootv;
    for (int h = H - 1; h >= 0; --h) {
        float nv   = (h == H - 1) ? bootv : values[b * H + h + 1];
        float mask = 1.0f - dones[b * H + h];
        g = rewards[b * H + h] + gamma * mask * (oml * nv + lam * g);
        returns[b * H + h] = g;
    }
}

__global__ __launch_bounds__(256) void loss_moments(
    const float* __restrict__ logits, const float* __restrict__ logZ,
    const float* __restrict__ values, const float* __restrict__ returns,
    double* __restrict__ accum, int NR)
{
    int row = blockIdx.x * blockDim.x + threadIdx.x;
    double lsum = 0, vsum = 0, v2 = 0, rsum = 0, r2 = 0;
    if (row < NR) {
        float v   = values[row];
        float ret = returns[row];
        float cl  = fminf(fmaxf(ret, BIN_LO_F), BIN_HI_F);
        const float step = (float)(40.0 / 254.0);
        float pos = (cl - BIN_LO_F) / step;
        int low = (int)floorf(pos);
        low = min(max(low, 0), NBINS - 2);
        float frac = pos - (float)low;
        const float* lp = logits + (size_t)row * NBINS;
        float llo = lp[low], lhi = lp[low + 1];
        float loss = logZ[row] - (1.f - frac) * llo - frac * lhi;
        lsum = (double)loss;
        vsum = (double)v;   v2 = (double)v * (double)v;
        rsum = (double)ret; r2 = (double)ret * (double)ret;
    }
    lsum = wave_reduce_sum_d(lsum);
    vsum = wave_reduce_sum_d(vsum);
    v2   = wave_reduce_sum_d(v2);
    rsum = wave_reduce_sum_d(rsum);
    r2   = wave_reduce_sum_d(r2);
    if ((threadIdx.x & 63) == 0) {
        atomicAdd(&accum[0], lsum);
        atomicAdd(&accum[1], vsum);
        atomicAdd(&accum[2], v2);
        atomicAdd(&accum[3], rsum);
        atomicAdd(&accum[4], r2);
    }
}

__global__ void finalize_k(const double* __restrict__ accum,
                           float* __restrict__ out, int NR)
{
    if (threadIdx.x == 0 && blockIdx.x == 0) {
        double n  = (double)NR;
        double vl = accum[0] / n;
        double mv = accum[1] / n;
        double vv = (accum[2] - n * mv * mv) / (n - 1.0);
        double mr = accum[3] / n;
        double vr = (accum[4] - n * mr * mr) / (n - 1.0);
        out[0] = (float)(0.5 * vl);
        out[1] = (float)vl;
        out[2] = (float)mv;
        out[3] = (float)mr;
        out[4] = (float)sqrt(vv > 0.0 ? vv : 0.0);
        out[5] = (float)sqrt(vr > 0.0 ? vr : 0.0);
    }
}

extern "C" void kernel_launch(void* const* d_in, const int* in_sizes, int n_in,
                              void* d_out, int out_size, void* d_ws, size_t ws_size,
                              hipStream_t stream) {
    const float* latents = (const float*)d_in[0];
    const float* rewards = (const float*)d_in[1];
    const float* dones   = (const float*)d_in[2];
    const float* boot    = (const float*)d_in[3];
    const float* W       = (const float*)d_in[4];
    const float* bvec    = (const float*)d_in[5];
    float* out = (float*)d_out;

    const int BH = in_sizes[1];
    const int D  = in_sizes[0] / BH;
    const int B  = in_sizes[3] / D;
    const int H  = BH / B;
    const int NR = BH;
    const int R  = NR + B;

    char* ws = (char*)d_ws;
    size_t off = 0;
    float* logits = (float*)(ws + off); off += (size_t)R * NBINS * sizeof(float);
    off = (off + 255) & ~(size_t)255;
    float* values = (float*)(ws + off); off += (size_t)R * sizeof(float);
    float* logZ   = (float*)(ws + off); off += (size_t)R * sizeof(float);
    float* rets   = (float*)(ws + off); off += (size_t)NR * sizeof(float);
    off = (off + 255) & ~(size_t)255;
    double* accum = (double*)(ws + off); off += 64;
    off = (off + 255) & ~(size_t)255;
    char* WpackB  = ws + off; off += (size_t)(D / 32) * 16384;

    hipMemsetAsync(accum, 0, 64, stream);

    const int NT = D / 32;
    const int packUnits = NT * 1024;
    pack_w4<<<packUnits / 256, 256, 0, stream>>>(W, WpackB);

    const int nwg = R / 32;
    // ---- ablation probes (outputs scratch; overwritten by the real V0 below) ----
    gemm_abl<1><<<nwg, 256, 0, stream>>>(latents, boot, WpackB, bvec, logits, NR, R, D, nwg / 8);
    gemm_abl<2><<<nwg, 256, 0, stream>>>(latents, boot, WpackB, bvec, logits, NR, R, D, nwg / 8);
    gemm_abl<3><<<nwg, 256, 0, stream>>>(latents, boot, WpackB, bvec, logits, NR, R, D, nwg / 8);
    gemm_abl<4><<<nwg, 256, 0, stream>>>(latents, boot, WpackB, bvec, logits, NR, R, D, nwg / 8);
    // ---- real GEMM ----
    gemm_abl<0><<<nwg, 256, 0, stream>>>(latents, boot, WpackB, bvec, logits, NR, R, D, nwg / 8);

    softmax_stats<<<(R + 3) / 4, 256, 0, stream>>>(logits, values, logZ, R);
    lambda_returns_k<<<(B + 255) / 256, 256, 0, stream>>>(rewards, dones, values, rets, B, H, NR);
    loss_moments<<<(NR + 255) / 256, 256, 0, stream>>>(logits, logZ, values, rets, accum, NR);
    finalize_k<<<1, 64, 0, stream>>>(accum, out, NR);
}

// Round 10
// 171.138 us; speedup vs baseline: 3.0619x; 3.0619x over previous
//
#include <hip/hip_runtime.h>
#include <math.h>

#define NBINS 255
#define BIN_LO_F (-20.0f)
#define BIN_HI_F (20.0f)

typedef __attribute__((ext_vector_type(8))) short short8;
typedef __attribute__((ext_vector_type(16))) float f32x16;

__device__ __forceinline__ unsigned short f2bf(float f) {
    unsigned u = __builtin_bit_cast(unsigned, f);
    unsigned r = u + 0x7fffu + ((u >> 16) & 1u);
    return (unsigned short)(r >> 16);
}

__device__ __forceinline__ unsigned pkbf(float lo, float hi) {
    unsigned d;
    asm("v_cvt_pk_bf16_f32 %0, %1, %2" : "=v"(d) : "v"(lo), "v"(hi));
    return d;
}

__device__ __forceinline__ short8 mk8(unsigned a, unsigned b, unsigned c, unsigned d) {
    union { unsigned u[4]; short8 s; } t;
    t.u[0] = a; t.u[1] = b; t.u[2] = c; t.u[3] = d;
    return t.s;
}

__device__ __forceinline__ void glds16(const void* g, void* l) {
    __builtin_amdgcn_global_load_lds(
        (const __attribute__((address_space(1))) unsigned int*)g,
        (__attribute__((address_space(3))) unsigned int*)l, 16, 0, 0);
}

__device__ __forceinline__ double wave_reduce_sum_d(double v) {
    #pragma unroll
    for (int m = 32; m >= 1; m >>= 1) v += __shfl_xor(v, m, 64);
    return v;
}

// Pack W (D,255) fp32 -> bf16 image, one 16 KB block per K-step of 32:
// 16B unit u: kt=u>>10, v=u&1023: ks=v>>9, lh=(v>>8)&1, gcol=(v>>5)&7, c31=v&31.
// content elem e: k = kt*32 + ks*16 + lh*8 + e, col = gcol*32 + c31 (col 255 -> 0 pad).
__global__ __launch_bounds__(256) void pack_w4(
    const float* __restrict__ W, char* __restrict__ WpackB)
{
    int u = blockIdx.x * 256 + threadIdx.x;
    int kt = u >> 10;
    int v  = u & 1023;
    int ks = v >> 9;
    int lh = (v >> 8) & 1;
    int gcol = (v >> 5) & 7;
    int c31  = v & 31;
    int col  = gcol * 32 + c31;
    int k0   = kt * 32 + ks * 16 + lh * 8;
    short8 s;
    #pragma unroll
    for (int e = 0; e < 8; ++e)
        s[e] = (col < NBINS) ? (short)f2bf(W[(size_t)(k0 + e) * NBINS + col]) : (short)0;
    *(short8*)(WpackB + (size_t)u * 16) = s;
}

// v9 = v8 structure at 4 blocks/CU (16 waves/CU). BM=32 x BN=256, BK=32, grid R/32=544,
// 256 thr = 4 waves = 4 col-groups, wave tile 32x64. A: glds row-major full-line streaming,
// XOR-swizzled both sides, fp32 in LDS, cvt_pk on read. B: 4 glds/wave from packed image.
// 2 LDS buffers (40 KB -> 4 blocks/CU), 2-phase counted vmcnt (batch=5 -> vmcnt(5));
// latency hidden by cross-block TLP (4 independent barrier domains per CU).
__global__ __launch_bounds__(256, 4) void gemm_mfma_v9(
    const float* __restrict__ latents, const float* __restrict__ boot,
    const char* __restrict__ WpackB, const float* __restrict__ bvec,
    float* __restrict__ logits, int NR, int R, int D, int nwg8)
{
    __shared__ __align__(16) char ldsA[2][4096];
    __shared__ __align__(16) char ldsB[2][16384];

    const int tid  = threadIdx.x;
    const int wave = tid >> 6, lane = tid & 63;
    const int l31  = lane & 31, lhi = lane >> 5;
    const int NT   = D >> 5;                 // 128 K-steps of 32 (even)

    // XCD-aware bijective swizzle (544 % 8 == 0)
    int bid  = blockIdx.x;
    int work = (bid & 7) * nwg8 + (bid >> 3);
    const int row0 = work * 32;

    // A staging: lane -> row wave*8+(lane>>3), phys chunk lane&7; source chunk ^= row&7.
    const int arow_loc = (wave << 3) + (lane >> 3);          // 0..31
    const int arow = row0 + arow_loc;
    const float* arowp = (arow < NR) ? latents + (size_t)arow * D
                                     : boot + (size_t)(arow - NR) * D;
    const float* asrc = arowp + (((lane & 7) ^ (arow_loc & 7)) << 2);

    const int abase = l31 << 7;              // l31 * 128
    const int axor  = l31 & 7;

    f32x16 acc0, acc1;
    #pragma unroll
    for (int r = 0; r < 16; ++r) { acc0[r] = 0.f; acc1[r] = 0.f; }

#define STAGE(T, BUF) do {                                                  \
        glds16(asrc + (size_t)(T) * 32, &ldsA[BUF][(wave << 10) + (lane << 4)]); \
        const char* bs_ = WpackB + (size_t)(T) * 16384 + (wave << 12) + (lane << 4); \
        char* bd_ = &ldsB[BUF][(wave << 12) + (lane << 4)];                 \
        glds16(bs_,        bd_);                                            \
        glds16(bs_ + 1024, bd_ + 1024);                                     \
        glds16(bs_ + 2048, bd_ + 2048);                                     \
        glds16(bs_ + 3072, bd_ + 3072);                                     \
    } while (0)

#define COMPUTE(BUF) do {                                                   \
        const char* ab_ = &ldsA[BUF][0];                                    \
        const char* bb_ = &ldsB[BUF][0] + (wave << 10) + (l31 << 4);        \
        _Pragma("unroll")                                                   \
        for (int ks = 0; ks < 2; ++ks) {                                    \
            int c0_ = ks * 4 + lhi * 2;                                     \
            float4 f0_ = *(const float4*)(ab_ + abase + (((c0_ + 0) ^ axor) << 4)); \
            float4 f1_ = *(const float4*)(ab_ + abase + (((c0_ + 1) ^ axor) << 4)); \
            short8 a_  = mk8(pkbf(f0_.x, f0_.y), pkbf(f0_.z, f0_.w),        \
                             pkbf(f1_.x, f1_.y), pkbf(f1_.z, f1_.w));       \
            short8 b0_ = *(const short8*)(bb_ + ((ks * 2 + lhi) << 12));    \
            short8 b1_ = *(const short8*)(bb_ + ((ks * 2 + lhi) << 12) + 512); \
            acc0 = __builtin_amdgcn_mfma_f32_32x32x16_bf16(a_, b0_, acc0, 0, 0, 0); \
            acc1 = __builtin_amdgcn_mfma_f32_32x32x16_bf16(a_, b1_, acc1, 0, 0, 0); \
        }                                                                   \
    } while (0)

#define BAR()   __builtin_amdgcn_s_barrier()
#define SCHED() __builtin_amdgcn_sched_barrier(0)
#define WAITV5() asm volatile("s_waitcnt vmcnt(5)" ::: "memory")
#define WAITV0() asm volatile("s_waitcnt vmcnt(0)" ::: "memory")

    // prologue
    STAGE(0, 0);

    int t = 0;
    for (; t + 3 < NT; t += 2) {
        BAR(); SCHED(); STAGE(t + 1, 1); SCHED(); WAITV5(); BAR(); SCHED(); COMPUTE(0);
        BAR(); SCHED(); STAGE(t + 2, 0); SCHED(); WAITV5(); BAR(); SCHED(); COMPUTE(1);
    }
    // t == NT-2: tiles NT-2 (buf0 staged), NT-1 (stage now)
    BAR(); SCHED(); STAGE(NT - 1, 1); SCHED(); WAITV5(); BAR(); SCHED(); COMPUTE(0);
    BAR(); SCHED(); WAITV0(); BAR(); SCHED(); COMPUTE(1);

#undef STAGE
#undef COMPUTE
#undef BAR
#undef SCHED
#undef WAITV5
#undef WAITV0

    // epilogue: wave's 32x64 tile. C layout: col=lane&31, row=(r&3)+8*(r>>2)+4*lhi
    #pragma unroll
    for (int i = 0; i < 2; ++i) {
        int col = wave * 64 + i * 32 + l31;
        if (col < NBINS) {
            float bias = bvec[col];
            const f32x16& a = i ? acc1 : acc0;
            #pragma unroll
            for (int r = 0; r < 16; ++r) {
                int row = row0 + (r & 3) + 8 * (r >> 2) + 4 * lhi;
                logits[(size_t)row * NBINS + col] = a[r] + bias;
            }
        }
    }
}

// per-row softmax stats: value = softmax(l)@centers, logZ
__global__ __launch_bounds__(256) void softmax_stats(
    const float* __restrict__ logits, float* __restrict__ values,
    float* __restrict__ logZ, int R)
{
    int row  = blockIdx.x * 4 + (threadIdx.x >> 6);
    int lane = threadIdx.x & 63;
    if (row >= R) return;
    const float* lp = logits + (size_t)row * NBINS;
    const float step = (float)(40.0 / 254.0);

    float l[4];
    float m = -INFINITY;
    #pragma unroll
    for (int u = 0; u < 4; ++u) {
        int idx = lane + 64 * u;
        l[u] = (idx < NBINS) ? lp[idx] : -INFINITY;
        m = fmaxf(m, l[u]);
    }
    #pragma unroll
    for (int sh = 32; sh >= 1; sh >>= 1) m = fmaxf(m, __shfl_xor(m, sh, 64));

    float s = 0.f, sc = 0.f;
    #pragma unroll
    for (int u = 0; u < 4; ++u) {
        int idx = lane + 64 * u;
        if (idx < NBINS) {
            float e = __expf(l[u] - m);
            s  += e;
            sc += e * (BIN_LO_F + step * (float)idx);
        }
    }
    #pragma unroll
    for (int sh = 32; sh >= 1; sh >>= 1) {
        s  += __shfl_xor(s, sh, 64);
        sc += __shfl_xor(sc, sh, 64);
    }
    if (lane == 0) {
        values[row] = sc / s;
        logZ[row]   = m + __logf(s);
    }
}

__global__ void lambda_returns_k(
    const float* __restrict__ rewards, const float* __restrict__ dones,
    const float* __restrict__ values, float* __restrict__ returns,
    int B, int H, int NR)
{
    int b = blockIdx.x * blockDim.x + threadIdx.x;
    if (b >= B) return;
    const float gamma = 0.997f;
    const float lam   = 0.95f;
    const float oml   = (float)(1.0 - 0.95);
    float bootv = values[NR + b];
    float g = bootv;
    for (int h = H - 1; h >= 0; --h) {
        float nv   = (h == H - 1) ? bootv : values[b * H + h + 1];
        float mask = 1.0f - dones[b * H + h];
        g = rewards[b * H + h] + gamma * mask * (oml * nv + lam * g);
        returns[b * H + h] = g;
    }
}

__global__ __launch_bounds__(256) void loss_moments(
    const float* __restrict__ logits, const float* __restrict__ logZ,
    const float* __restrict__ values, const float* __restrict__ returns,
    double* __restrict__ accum, int NR)
{
    int row = blockIdx.x * blockDim.x + threadIdx.x;
    double lsum = 0, vsum = 0, v2 = 0, rsum = 0, r2 = 0;
    if (row < NR) {
        float v   = values[row];
        float ret = returns[row];
        float cl  = fminf(fmaxf(ret, BIN_LO_F), BIN_HI_F);
        const float step = (float)(40.0 / 254.0);
        float pos = (cl - BIN_LO_F) / step;
        int low = (int)floorf(pos);
        low = min(max(low, 0), NBINS - 2);
        float frac = pos - (float)low;
        const float* lp = logits + (size_t)row * NBINS;
        float llo = lp[low], lhi = lp[low + 1];
        float loss = logZ[row] - (1.f - frac) * llo - frac * lhi;
        lsum = (double)loss;
        vsum = (double)v;   v2 = (double)v * (double)v;
        rsum = (double)ret; r2 = (double)ret * (double)ret;
    }
    lsum = wave_reduce_sum_d(lsum);
    vsum = wave_reduce_sum_d(vsum);
    v2   = wave_reduce_sum_d(v2);
    rsum = wave_reduce_sum_d(rsum);
    r2   = wave_reduce_sum_d(r2);
    if ((threadIdx.x & 63) == 0) {
        atomicAdd(&accum[0], lsum);
        atomicAdd(&accum[1], vsum);
        atomicAdd(&accum[2], v2);
        atomicAdd(&accum[3], rsum);
        atomicAdd(&accum[4], r2);
    }
}

__global__ void finalize_k(const double* __restrict__ accum,
                           float* __restrict__ out, int NR)
{
    if (threadIdx.x == 0 && blockIdx.x == 0) {
        double n  = (double)NR;
        double vl = accum[0] / n;
        double mv = accum[1] / n;
        double vv = (accum[2] - n * mv * mv) / (n - 1.0);
        double mr = accum[3] / n;
        double vr = (accum[4] - n * mr * mr) / (n - 1.0);
        out[0] = (float)(0.5 * vl);
        out[1] = (float)vl;
        out[2] = (float)mv;
        out[3] = (float)mr;
        out[4] = (float)sqrt(vv > 0.0 ? vv : 0.0);
        out[5] = (float)sqrt(vr > 0.0 ? vr : 0.0);
    }
}

extern "C" void kernel_launch(void* const* d_in, const int* in_sizes, int n_in,
                              void* d_out, int out_size, void* d_ws, size_t ws_size,
                              hipStream_t stream) {
    const float* latents = (const float*)d_in[0];
    const float* rewards = (const float*)d_in[1];
    const float* dones   = (const float*)d_in[2];
    const float* boot    = (const float*)d_in[3];
    const float* W       = (const float*)d_in[4];
    const float* bvec    = (const float*)d_in[5];
    float* out = (float*)d_out;

    const int BH = in_sizes[1];          // B*H = 16384
    const int D  = in_sizes[0] / BH;     // 4096
    const int B  = in_sizes[3] / D;      // 1024
    const int H  = BH / B;               // 16
    const int NR = BH;
    const int R  = NR + B;               // 17408

    char* ws = (char*)d_ws;
    size_t off = 0;
    float* logits = (float*)(ws + off); off += (size_t)R * NBINS * sizeof(float);
    off = (off + 255) & ~(size_t)255;
    float* values = (float*)(ws + off); off += (size_t)R * sizeof(float);
    float* logZ   = (float*)(ws + off); off += (size_t)R * sizeof(float);
    float* rets   = (float*)(ws + off); off += (size_t)NR * sizeof(float);
    off = (off + 255) & ~(size_t)255;
    double* accum = (double*)(ws + off); off += 64;
    off = (off + 255) & ~(size_t)255;
    char* WpackB  = ws + off; off += (size_t)(D / 32) * 16384;   // 2 MB

    hipMemsetAsync(accum, 0, 64, stream);

    const int NT = D / 32;
    const int packUnits = NT * 1024;                 // 16B units
    pack_w4<<<packUnits / 256, 256, 0, stream>>>(W, WpackB);

    const int nwg = R / 32;                          // 544
    gemm_mfma_v9<<<nwg, 256, 0, stream>>>(latents, boot, WpackB, bvec, logits,
                                          NR, R, D, nwg / 8);
    softmax_stats<<<(R + 3) / 4, 256, 0, stream>>>(logits, values, logZ, R);
    lambda_returns_k<<<(B + 255) / 256, 256, 0, stream>>>(rewards, dones, values, rets, B, H, NR);
    loss_moments<<<(NR + 255) / 256, 256, 0, stream>>>(logits, logZ, values, rets, accum, NR);
    finalize_k<<<1, 64, 0, stream>>>(accum, out, NR);
}